// Round 4
// baseline (6013.838 us; speedup 1.0000x reference)
//
#include <hip/hip_runtime.h>
#include <math.h>

// ---------------------------------------------------------------------------
// TE-SNN forward, round 4: LDS-free step GEMMs (scalar spike operands).
//  Bit-exactness invariants (established r3): per-output single ascending-j
//  fmac chain; exact numpy elementwise order via __f*_rn; CR cosf/powf.
//  k_step2: lane=i, n-group 8 per block (blockIdx-uniform -> s_load spikes),
//  w streamed per-lane from L2. Spikes kept in [n][i] (layer2 state) and
//  transposed [j][n] (GEMM operand) layouts. Readout fused in layer-2 blocks.
// ---------------------------------------------------------------------------

#define T_STEPS 101
#define NB      512
#define INSZ    700
#define H       512
#define OUTSZ   20

__global__ __launch_bounds__(256) void k_prep(
    const float* __restrict__ wr, const float* __restrict__ w2,
    const float* __restrict__ fre,
    float* __restrict__ wrT, float* __restrict__ w2T,
    float* __restrict__ ce,
    float* __restrict__ mem1, float* __restrict__ th1,
    float* __restrict__ mem2, float* __restrict__ th2, float* __restrict__ sp2,
    float* __restrict__ spTa, float* __restrict__ spTb,
    float* __restrict__ osum)
{
  const int idx    = (int)(blockIdx.x * blockDim.x + threadIdx.x);
  const int stride = (int)(gridDim.x * blockDim.x);
  // exact transposes: wT[j][i] = w[i][j]
  for (int p = idx; p < H * H; p += stride) {
    const int j = p >> 9, i = p & 511;
    wrT[p] = wr[(size_t)i * H + j];
    w2T[p] = w2[(size_t)i * H + j];
  }
  // ce[t][i], faithful f32 pipeline; pow/cos correctly rounded via f64
  for (int p = idx; p < T_STEPS * H; p += stride) {
    const int t = p >> 9, i = p & 511;
    const float e   = __fdiv_rn((float)i, 512.0f);
    const float pw  = (float)pow(100.0, (double)e);
    const float dtv = __fdiv_rn(0.1f, pw);
    const float fd  = __fmul_rn(fre[i], dtv);
    const float a   = __fmul_rn(fd, (float)t);
    const float cc  = (float)cos((double)a);
    ce[p] = __fmul_rn(cc, 0.1f);
  }
  for (int p = idx; p < NB * H; p += stride) {
    mem1[p] = 0.f; th1[p] = 0.5f;
    mem2[p] = 0.f; th2[p] = 0.5f; sp2[p] = 0.f;
    spTa[p] = 0.f; spTb[p] = 0.f;
  }
  for (int p = idx; p < NB * OUTSZ; p += stride) osum[p] = 0.f;
}

// A1[m][i] = sum_k input[m][k]*w1[i][k], single fma chain ascending k.
// grid (4, 404), 256 threads, 128x128 tile, BK=8.
// n-microtile remapped to tx+16q: stride-1 LDS reads (conflict-free).
__global__ __launch_bounds__(256) void k_ingemm(
    const float* __restrict__ A, const float* __restrict__ W,
    float* __restrict__ C)
{
  __shared__ float sA[8][128];
  __shared__ float sB[8][128];
  const int tid = (int)threadIdx.x;
  const int bn = (int)blockIdx.x;
  const int bm = (int)blockIdx.y;
  const int tx = tid & 15, ty = tid >> 4;
  const int lr = tid >> 1;
  const int lc = (tid & 1) * 4;
  const float* Arow = A + (size_t)(bm * 128 + lr) * INSZ;
  const float* Wrow = W + (size_t)(bn * 128 + lr) * INSZ;
  float acc[8][8];
#pragma unroll
  for (int a = 0; a < 8; ++a)
#pragma unroll
    for (int b = 0; b < 8; ++b) acc[a][b] = 0.f;

  for (int kt = 0; kt < INSZ; kt += 8) {
    const int kb = kt + lc;
    float4 av = make_float4(0.f, 0.f, 0.f, 0.f);
    float4 bv = make_float4(0.f, 0.f, 0.f, 0.f);
    if (kb < INSZ) {
      av = *reinterpret_cast<const float4*>(Arow + kb);
      bv = *reinterpret_cast<const float4*>(Wrow + kb);
    }
    __syncthreads();
    sA[lc + 0][lr] = av.x; sA[lc + 1][lr] = av.y; sA[lc + 2][lr] = av.z; sA[lc + 3][lr] = av.w;
    sB[lc + 0][lr] = bv.x; sB[lc + 1][lr] = bv.y; sB[lc + 2][lr] = bv.z; sB[lc + 3][lr] = bv.w;
    __syncthreads();
#pragma unroll
    for (int kk = 0; kk < 8; ++kk) {
      float a[8], b[8];
#pragma unroll
      for (int q = 0; q < 8; ++q) a[q] = sA[kk][ty * 8 + q];       // broadcast (free)
#pragma unroll
      for (int q = 0; q < 8; ++q) b[q] = sB[kk][tx + 16 * q];      // stride-1, no conflict
#pragma unroll
      for (int m = 0; m < 8; ++m)
#pragma unroll
        for (int n = 0; n < 8; ++n) acc[m][n] = fmaf(a[m], b[n], acc[m][n]);
    }
  }
#pragma unroll
  for (int m = 0; m < 8; ++m) {
    float* crow = C + (size_t)(bm * 128 + ty * 8 + m) * H + bn * 128 + tx;
#pragma unroll
    for (int q = 0; q < 8; ++q) crow[16 * q] = acc[m][q];
  }
}

// Skewed step kernel v2. z==1: layer1(tt). z==0: layer2(tt-1) + readout.
// Block: 256 threads = 4 waves; lane covers i (iG = bx*256+tid),
// n-group of 8 (n0 = by*8, blockIdx-uniform -> scalar spike loads).
__global__ __launch_bounds__(256) void k_step2(
    const float* __restrict__ A1,
    const float* __restrict__ wrT, const float* __restrict__ w2T,
    const float* __restrict__ wo,
    const float* __restrict__ b1, const float* __restrict__ br,
    const float* __restrict__ b2, const float* __restrict__ bo,
    const float* __restrict__ ce,
    const float* __restrict__ spTR,  // sp1^T after step tt-1   [j][n]
    float* __restrict__ spTW,        // sp1^T after step tt
    float* __restrict__ mem1, float* __restrict__ th1,
    float* __restrict__ mem2, float* __restrict__ th2,
    float* __restrict__ sp2,         // [n][i]
    float* __restrict__ osum,
    const int tt)
{
  const int z = (int)blockIdx.z;
  const int t = z ? tt : (tt - 1);
  if (z && t >= T_STEPS) return;
  if (!z && t < 0) return;

  const int tid = (int)threadIdx.x;
  const int bx  = (int)blockIdx.x;       // 0,1: i-half
  const int n0  = (int)blockIdx.y * 8;   // n-group (uniform)
  const int iG  = bx * 256 + tid;

  const float* WT    = z ? wrT : w2T;
  const float* sprow = spTR + n0;

  float acc[8];
#pragma unroll
  for (int q = 0; q < 8; ++q) acc[q] = 0.f;

#pragma unroll 4
  for (int j = 0; j < H; ++j) {
    const float wv = WT[(size_t)j * H + iG];          // per-lane, coalesced
    const float* s = sprow + (size_t)j * H;           // wave-uniform -> s_load
#pragma unroll
    for (int q = 0; q < 8; ++q) acc[q] = fmaf(s[q], wv, acc[q]);
  }

  const float cv = ce[(size_t)t * H + iG];

  if (z) {
    // ---- layer 1, step t = tt ----
    const float4 so0 = *reinterpret_cast<const float4*>(spTR + (size_t)iG * H + n0);
    const float4 so1 = *reinterpret_cast<const float4*>(spTR + (size_t)iG * H + n0 + 4);
    const float so[8] = {so0.x, so0.y, so0.z, so0.w, so1.x, so1.y, so1.z, so1.w};
    const float b1v = b1[iG], brv = br[iG];
    float sn[8];
#pragma unroll
    for (int q = 0; q < 8; ++q) {
      const size_t p = (size_t)(n0 + q) * H + iG;
      const float d1 = A1[((size_t)t * NB + n0 + q) * H + iG];
      // h = ((d1 + b1) + d2) + br
      const float h = __fadd_rn(__fadd_rn(__fadd_rn(d1, b1v), acc[q]), brv);
      const float m  = mem1[p];
      const float th = th1[p];
      const float thn = __fsub_rn(__fadd_rn(th, __fmul_rn(m, cv)),
                                  __fmul_rn(__fsub_rn(th, 0.5f), 0.02f));
      const float mn  = __fadd_rn(__fmul_rn(__fmul_rn(m, 0.5f), __fsub_rn(1.0f, so[q])), h);
      mem1[p] = mn;
      th1[p]  = thn;
      sn[q]   = (mn > thn) ? 1.0f : 0.0f;
    }
    *reinterpret_cast<float4*>(spTW + (size_t)iG * H + n0)     = make_float4(sn[0], sn[1], sn[2], sn[3]);
    *reinterpret_cast<float4*>(spTW + (size_t)iG * H + n0 + 4) = make_float4(sn[4], sn[5], sn[6], sn[7]);
  } else {
    // ---- layer 2 + readout, step t = tt-1 ----
    __shared__ float lsp[256][13];
    const float b2v = b2[iG];
#pragma unroll
    for (int q = 0; q < 8; ++q) {
      const size_t p = (size_t)(n0 + q) * H + iG;
      const float h  = __fadd_rn(acc[q], b2v);
      const float m  = mem2[p];
      const float th = th2[p];
      const float so = sp2[p];
      const float thn = __fsub_rn(__fadd_rn(th, __fmul_rn(m, cv)),
                                  __fmul_rn(__fsub_rn(th, 0.5f), 0.02f));
      const float mn  = __fadd_rn(__fmul_rn(__fmul_rn(m, 0.5f), __fsub_rn(1.0f, so)), h);
      const float sn  = (mn > thn) ? 1.0f : 0.0f;
      mem2[p] = mn;
      th2[p]  = thn;
      sp2[p]  = sn;
      lsp[tid][q] = sn;
    }
    __syncthreads();
    if (tid < 8 * OUTSZ) {
      const int q = tid & 7;
      const int o = tid >> 3;
      const float* worow = wo + (size_t)o * H + bx * 256;
      float s = 0.f;
      for (int ii = 0; ii < 256; ++ii) s = fmaf(lsp[ii][q], worow[ii], s);
      if (bx == 0) s = __fadd_rn(s, bo[o]);
      atomicAdd(osum + (size_t)(n0 + q) * OUTSZ + o, s);
    }
  }
}

__global__ __launch_bounds__(256) void k_final(
    const float* __restrict__ osum, float* __restrict__ out)
{
  const int p = (int)(blockIdx.x * 256 + threadIdx.x);
  if (p < NB * OUTSZ) out[p] = __fdiv_rn(osum[p], 101.0f);
}

extern "C" void kernel_launch(void* const* d_in, const int* in_sizes, int n_in,
                              void* d_out, int out_size, void* d_ws, size_t ws_size,
                              hipStream_t stream)
{
  (void)in_sizes; (void)n_in; (void)out_size; (void)ws_size;
  const float* input = (const float*)d_in[0];
  const float* w1    = (const float*)d_in[1];
  const float* b1    = (const float*)d_in[2];
  const float* wr    = (const float*)d_in[3];
  const float* br    = (const float*)d_in[4];
  const float* w2    = (const float*)d_in[5];
  const float* b2    = (const float*)d_in[6];
  const float* wo    = (const float*)d_in[7];
  const float* bo    = (const float*)d_in[8];
  const float* fre   = (const float*)d_in[9];

  float* ws = (float*)d_ws;
  size_t off = 0;
  float* A1   = ws + off; off += (size_t)T_STEPS * NB * H;   // 26,476,544
  float* ce   = ws + off; off += (size_t)T_STEPS * H;
  float* wrT  = ws + off; off += (size_t)H * H;
  float* w2T  = ws + off; off += (size_t)H * H;
  float* mem1 = ws + off; off += (size_t)NB * H;
  float* th1  = ws + off; off += (size_t)NB * H;
  float* mem2 = ws + off; off += (size_t)NB * H;
  float* th2  = ws + off; off += (size_t)NB * H;
  float* sp2  = ws + off; off += (size_t)NB * H;
  float* spTa = ws + off; off += (size_t)NB * H;
  float* spTb = ws + off; off += (size_t)NB * H;
  float* osum = ws + off; off += (size_t)NB * OUTSZ;
  // total 28,897,792 floats = 115.6 MB

  k_prep<<<1024, 256, 0, stream>>>(wr, w2, fre, wrT, w2T, ce,
                                   mem1, th1, mem2, th2, sp2, spTa, spTb, osum);
  k_ingemm<<<dim3(4, 404), 256, 0, stream>>>(input, w1, A1);

  for (int tt = 0; tt <= T_STEPS; ++tt) {
    float* spTR = (tt & 1) ? spTb : spTa;   // sp1^T after step tt-1
    float* spTW = (tt & 1) ? spTa : spTb;   // sp1^T after step tt
    k_step2<<<dim3(2, 64, 2), 256, 0, stream>>>(
        A1, wrT, w2T, wo, b1, br, b2, bo, ce, spTR, spTW,
        mem1, th1, mem2, th2, sp2, osum, tt);
  }

  k_final<<<40, 256, 0, stream>>>(osum, (float*)d_out);
}

// Round 5
// 3348.042 us; speedup vs baseline: 1.7962x; 1.7962x over previous
//
#include <hip/hip_runtime.h>
#include <math.h>

// ---------------------------------------------------------------------------
// TE-SNN forward, round 5.
//  Bit-exactness invariants (r3): per-output single ascending-j chain; exact
//  numpy elementwise order (__f*_rn); CR cosf/powf. NEW (r5): zero-spike
//  skipping is bit-exact (fmaf(0,w,acc)==acc, acc never -0; fmaf(1,w,acc)==
//  fadd(acc,w)), so spike GEMMs become bitmask-driven sparse row-sums.
//  k_step3: 1 (n,i) per thread, grid (2,512,2) -> 32 waves/CU. Spikes in
//  [n][j] layout + 512-bit fire masks per row (ballot in producer).
// ---------------------------------------------------------------------------

#define T_STEPS 101
#define NB      512
#define INSZ    700
#define H       512
#define OUTSZ   20

__global__ __launch_bounds__(256) void k_prep(
    const float* __restrict__ wr, const float* __restrict__ w2,
    const float* __restrict__ wo, const float* __restrict__ fre,
    float* __restrict__ wrT, float* __restrict__ w2T, float* __restrict__ woT,
    float* __restrict__ ce,
    float* __restrict__ mem1, float* __restrict__ th1,
    float* __restrict__ mem2, float* __restrict__ th2, float* __restrict__ sp2,
    float* __restrict__ spA,
    unsigned* __restrict__ mA, unsigned* __restrict__ mB,
    float* __restrict__ osum)
{
  const int idx    = (int)(blockIdx.x * blockDim.x + threadIdx.x);
  const int stride = (int)(gridDim.x * blockDim.x);
  for (int p = idx; p < H * H; p += stride) {
    const int j = p >> 9, i = p & 511;
    wrT[p] = wr[(size_t)i * H + j];
    w2T[p] = w2[(size_t)i * H + j];
  }
  for (int p = idx; p < H * OUTSZ; p += stride) {
    const int i = p / OUTSZ, o = p - i * OUTSZ;
    woT[p] = wo[(size_t)o * H + i];
  }
  // ce[t][i], faithful f32 pipeline; pow/cos correctly rounded via f64
  for (int p = idx; p < T_STEPS * H; p += stride) {
    const int t = p >> 9, i = p & 511;
    const float e   = __fdiv_rn((float)i, 512.0f);
    const float pw  = (float)pow(100.0, (double)e);
    const float dtv = __fdiv_rn(0.1f, pw);
    const float fd  = __fmul_rn(fre[i], dtv);
    const float a   = __fmul_rn(fd, (float)t);
    const float cc  = (float)cos((double)a);
    ce[p] = __fmul_rn(cc, 0.1f);
  }
  for (int p = idx; p < NB * H; p += stride) {
    mem1[p] = 0.f; th1[p] = 0.5f;
    mem2[p] = 0.f; th2[p] = 0.5f; sp2[p] = 0.f;
    spA[p] = 0.f;
  }
  for (int p = idx; p < NB * 16; p += stride) { mA[p] = 0u; mB[p] = 0u; }
  for (int p = idx; p < NB * OUTSZ; p += stride) osum[p] = 0.f;
}

// A1[m][i] = sum_k input[m][k]*w1[i][k], single fma chain ascending k.
// r3 structure (known 513us) + float4 LDS reads (4x fewer DS issues).
__global__ __launch_bounds__(256) void k_ingemm(
    const float* __restrict__ A, const float* __restrict__ W,
    float* __restrict__ C)
{
  __shared__ float sA[8][128];
  __shared__ float sB[8][128];
  const int tid = (int)threadIdx.x;
  const int bn = (int)blockIdx.x;
  const int bm = (int)blockIdx.y;
  const int tx = tid & 15, ty = tid >> 4;
  const int lr = tid >> 1;
  const int lc = (tid & 1) * 4;
  const float* Arow = A + (size_t)(bm * 128 + lr) * INSZ;
  const float* Wrow = W + (size_t)(bn * 128 + lr) * INSZ;
  float acc[8][8];
#pragma unroll
  for (int a = 0; a < 8; ++a)
#pragma unroll
    for (int b = 0; b < 8; ++b) acc[a][b] = 0.f;

  for (int kt = 0; kt < INSZ; kt += 8) {
    const int kb = kt + lc;
    float4 av = make_float4(0.f, 0.f, 0.f, 0.f);
    float4 bv = make_float4(0.f, 0.f, 0.f, 0.f);
    if (kb < INSZ) {
      av = *reinterpret_cast<const float4*>(Arow + kb);
      bv = *reinterpret_cast<const float4*>(Wrow + kb);
    }
    __syncthreads();
    sA[lc + 0][lr] = av.x; sA[lc + 1][lr] = av.y; sA[lc + 2][lr] = av.z; sA[lc + 3][lr] = av.w;
    sB[lc + 0][lr] = bv.x; sB[lc + 1][lr] = bv.y; sB[lc + 2][lr] = bv.z; sB[lc + 3][lr] = bv.w;
    __syncthreads();
#pragma unroll
    for (int kk = 0; kk < 8; ++kk) {
      const float4 a0 = *reinterpret_cast<const float4*>(&sA[kk][ty * 8]);
      const float4 a1 = *reinterpret_cast<const float4*>(&sA[kk][ty * 8 + 4]);
      const float4 b0 = *reinterpret_cast<const float4*>(&sB[kk][tx * 8]);
      const float4 b1 = *reinterpret_cast<const float4*>(&sB[kk][tx * 8 + 4]);
      const float a[8] = {a0.x, a0.y, a0.z, a0.w, a1.x, a1.y, a1.z, a1.w};
      const float b[8] = {b0.x, b0.y, b0.z, b0.w, b1.x, b1.y, b1.z, b1.w};
#pragma unroll
      for (int m = 0; m < 8; ++m)
#pragma unroll
        for (int n = 0; n < 8; ++n) acc[m][n] = fmaf(a[m], b[n], acc[m][n]);
    }
  }
  const int col0 = bn * 128 + tx * 8;
#pragma unroll
  for (int m = 0; m < 8; ++m) {
    float* crow = C + (size_t)(bm * 128 + ty * 8 + m) * H + col0;
    *reinterpret_cast<float4*>(crow)     = make_float4(acc[m][0], acc[m][1], acc[m][2], acc[m][3]);
    *reinterpret_cast<float4*>(crow + 4) = make_float4(acc[m][4], acc[m][5], acc[m][6], acc[m][7]);
  }
}

// Skewed step v3. z==1: layer1(tt). z==0: layer2(tt-1)+readout.
// Block: 256 threads = one n (blockIdx.y), i-half (blockIdx.x). Sparse
// mask-driven row-sum GEMM; full occupancy (8 blocks/CU).
__global__ __launch_bounds__(256) void k_step3(
    const float* __restrict__ A1,
    const float* __restrict__ wrT, const float* __restrict__ w2T,
    const float* __restrict__ woT,
    const float* __restrict__ b1, const float* __restrict__ br,
    const float* __restrict__ b2, const float* __restrict__ bo,
    const float* __restrict__ ce,
    const float* __restrict__ spR,     // sp1 [n][j] after tt-1
    const unsigned* __restrict__ mR,   // fire mask [n][16] after tt-1
    float* __restrict__ spW,           // sp1 [n][j] after tt
    unsigned* __restrict__ mW,
    float* __restrict__ mem1, float* __restrict__ th1,
    float* __restrict__ mem2, float* __restrict__ th2,
    float* __restrict__ sp2,           // [n][i]
    float* __restrict__ osum,
    const int tt)
{
  const int z = (int)blockIdx.z;
  const int t = z ? tt : (tt - 1);
  if (z) { if (t >= T_STEPS) return; }
  else   { if (t < 0) return; }

  const int tid = (int)threadIdx.x;
  const int bx  = (int)blockIdx.x;        // i-half
  const int n   = (int)blockIdx.y;        // batch row (uniform)
  const int iG  = bx * 256 + tid;

  const float* WT = z ? wrT : w2T;
  const unsigned* mrow = mR + (size_t)n * 16;

  // sparse ascending-j row sum: bit-exact vs dense fma chain
  float acc = 0.f;
#pragma unroll 4
  for (int wd = 0; wd < 16; ++wd) {
    unsigned m = mrow[wd];
    const int jb = wd * 32;
    while (m) {
      const int b = __builtin_ctz(m);
      m &= m - 1;
      acc = __fadd_rn(acc, WT[(size_t)(jb + b) * H + iG]);
    }
  }

  const float cv = ce[(size_t)t * H + iG];
  const size_t p = (size_t)n * H + iG;

  if (z) {
    // ---- layer 1, step t = tt ----
    const float d1  = A1[((size_t)t * NB + n) * H + iG];
    const float h   = __fadd_rn(__fadd_rn(__fadd_rn(d1, b1[iG]), acc), br[iG]);
    const float m   = mem1[p];
    const float th  = th1[p];
    const float so  = spR[p];
    const float thn = __fsub_rn(__fadd_rn(th, __fmul_rn(m, cv)),
                                __fmul_rn(__fsub_rn(th, 0.5f), 0.02f));
    const float mn  = __fadd_rn(__fmul_rn(__fmul_rn(m, 0.5f), __fsub_rn(1.0f, so)), h);
    const float sn  = (mn > thn) ? 1.0f : 0.0f;
    mem1[p] = mn;
    th1[p]  = thn;
    spW[p]  = sn;
    const unsigned long long bal = __ballot(sn != 0.0f);
    if ((tid & 31) == 0) {
      const unsigned v = (tid & 32) ? (unsigned)(bal >> 32) : (unsigned)bal;
      mW[(size_t)n * 16 + (iG >> 5)] = v;
    }
  } else {
    // ---- layer 2 + readout, step t = tt-1 ----
    __shared__ float lsp[256];
    const float h   = __fadd_rn(acc, b2[iG]);
    const float m   = mem2[p];
    const float th  = th2[p];
    const float so  = sp2[p];
    const float thn = __fsub_rn(__fadd_rn(th, __fmul_rn(m, cv)),
                                __fmul_rn(__fsub_rn(th, 0.5f), 0.02f));
    const float mn  = __fadd_rn(__fmul_rn(__fmul_rn(m, 0.5f), __fsub_rn(1.0f, so)), h);
    const float sn  = (mn > thn) ? 1.0f : 0.0f;
    mem2[p] = mn;
    th2[p]  = thn;
    sp2[p]  = sn;
    lsp[tid] = sn;
    __syncthreads();
    if (tid < OUTSZ) {
      float s = 0.f;
      const float* wcol = woT + (size_t)bx * 256 * OUTSZ + tid;
      for (int ii = 0; ii < 256; ++ii)
        s = fmaf(lsp[ii], wcol[(size_t)ii * OUTSZ], s);
      if (bx == 0) s = __fadd_rn(s, bo[tid]);
      atomicAdd(osum + (size_t)n * OUTSZ + tid, s);
    }
  }
}

__global__ __launch_bounds__(256) void k_final(
    const float* __restrict__ osum, float* __restrict__ out)
{
  const int p = (int)(blockIdx.x * 256 + threadIdx.x);
  if (p < NB * OUTSZ) out[p] = __fdiv_rn(osum[p], 101.0f);
}

extern "C" void kernel_launch(void* const* d_in, const int* in_sizes, int n_in,
                              void* d_out, int out_size, void* d_ws, size_t ws_size,
                              hipStream_t stream)
{
  (void)in_sizes; (void)n_in; (void)out_size; (void)ws_size;
  const float* input = (const float*)d_in[0];
  const float* w1    = (const float*)d_in[1];
  const float* b1    = (const float*)d_in[2];
  const float* wr    = (const float*)d_in[3];
  const float* br    = (const float*)d_in[4];
  const float* w2    = (const float*)d_in[5];
  const float* b2    = (const float*)d_in[6];
  const float* wo    = (const float*)d_in[7];
  const float* bo    = (const float*)d_in[8];
  const float* fre   = (const float*)d_in[9];

  float* ws = (float*)d_ws;
  size_t off = 0;
  float* A1   = ws + off; off += (size_t)T_STEPS * NB * H;   // 26,476,544
  float* ce   = ws + off; off += (size_t)T_STEPS * H;
  float* wrT  = ws + off; off += (size_t)H * H;
  float* w2T  = ws + off; off += (size_t)H * H;
  float* woT  = ws + off; off += (size_t)H * OUTSZ;
  float* mem1 = ws + off; off += (size_t)NB * H;
  float* th1  = ws + off; off += (size_t)NB * H;
  float* mem2 = ws + off; off += (size_t)NB * H;
  float* th2  = ws + off; off += (size_t)NB * H;
  float* sp2  = ws + off; off += (size_t)NB * H;
  float* spA  = ws + off; off += (size_t)NB * H;
  float* spB  = ws + off; off += (size_t)NB * H;
  unsigned* mAm = (unsigned*)(ws + off); off += (size_t)NB * 16;
  unsigned* mBm = (unsigned*)(ws + off); off += (size_t)NB * 16;
  float* osum = ws + off; off += (size_t)NB * OUTSZ;
  // total ~115.7 MB

  k_prep<<<1024, 256, 0, stream>>>(wr, w2, wo, fre, wrT, w2T, woT, ce,
                                   mem1, th1, mem2, th2, sp2, spA, mAm, mBm, osum);
  k_ingemm<<<dim3(4, 404), 256, 0, stream>>>(input, w1, A1);

  for (int tt = 0; tt <= T_STEPS; ++tt) {
    // sp1/mask after step tt-1 in (A if tt even ? no:) ping-pong:
    float*    spR = (tt & 1) ? spB : spA;
    unsigned* mR  = (tt & 1) ? mBm : mAm;
    float*    spW = (tt & 1) ? spA : spB;
    unsigned* mW  = (tt & 1) ? mAm : mBm;
    k_step3<<<dim3(2, 512, 2), 256, 0, stream>>>(
        A1, wrT, w2T, woT, b1, br, b2, bo, ce, spR, mR, spW, mW,
        mem1, th1, mem2, th2, sp2, osum, tt);
  }

  k_final<<<40, 256, 0, stream>>>(osum, (float*)d_out);
}